// Round 1
// baseline (139.758 us; speedup 1.0000x reference)
//
#include <hip/hip_runtime.h>
#include <math.h>

// Problem constants (fixed by reference): B=16, C=128, H=W=32, N=1024,
// HEADS=4, DIM_HEAD=32, hid=128, qkv rows = 384.
#define NBATCH 16
#define CIN 128
#define NTOK 1024
#define QKV_ROWS 384
#define SCALE_Q 0.17677669529663687f  /* 32^-0.5 */
#define GN_EPS 1e-5f
#define PER_BATCH_ELEMS (CIN * NTOK)  /* 131072 */

// ---------------- workspace layout (floats) ----------------
// stats: [16][2]  (sum, sumsq)          @ 0        (zeroed each launch)
// M:     [16][4][32][32]                @ 32       (zeroed each launch)
// W2:    [16][128][128]                 @ 32+65536
// qkv:   [16][384][1024]                @ 32+65536+262144
#define WS_STATS 0
#define WS_M     32
#define WS_W2    (32 + 65536)
#define WS_QKV   (32 + 65536 + 262144)

// ---------------------------------------------------------------------------
// K1: per-batch sum / sumsq reduction. grid (16, 32), block 256.
__global__ __launch_bounds__(256) void k_stats(const float* __restrict__ x,
                                               float* __restrict__ stats) {
    int b = blockIdx.x, chunk = blockIdx.y;
    const float4* p = (const float4*)(x + (size_t)b * PER_BATCH_ELEMS + chunk * 4096);
    float s = 0.f, s2 = 0.f;
    for (int i = threadIdx.x; i < 1024; i += 256) {
        float4 v = p[i];
        s  += v.x + v.y + v.z + v.w;
        s2 += v.x * v.x + v.y * v.y + v.z * v.z + v.w * v.w;
    }
    for (int off = 32; off; off >>= 1) {
        s  += __shfl_down(s, off);
        s2 += __shfl_down(s2, off);
    }
    __shared__ float ls[4], ls2[4];
    int wid = threadIdx.x >> 6, lane = threadIdx.x & 63;
    if (lane == 0) { ls[wid] = s; ls2[wid] = s2; }
    __syncthreads();
    if (threadIdx.x == 0) {
        float t = 0, t2 = 0;
        for (int w = 0; w < 4; w++) { t += ls[w]; t2 += ls2[w]; }
        atomicAdd(&stats[b * 2], t);
        atomicAdd(&stats[b * 2 + 1], t2);
    }
}

// ---------------------------------------------------------------------------
// K2: qkv = w_qkv @ groupnorm(x).  per-batch 384x1024, K=128.
// grid (6, 16, 16) = (o-tiles, n-tiles, batch). block 256. 64x64 tile, full K in LDS.
__global__ __launch_bounds__(256) void k_qkv(const float* __restrict__ x,
                                             const float* __restrict__ gw,
                                             const float* __restrict__ gb,
                                             const float* __restrict__ wqkv,
                                             const float* __restrict__ stats,
                                             float* __restrict__ qkv) {
    __shared__ __align__(16) float aT[128][64];  // aT[k][o]
    __shared__ __align__(16) float bT[128][64];  // bT[k][n]
    int b = blockIdx.z;
    int o0 = blockIdx.x * 64;
    int n0 = blockIdx.y * 64;
    float mu  = stats[b * 2] * (1.f / PER_BATCH_ELEMS);
    float var = stats[b * 2 + 1] * (1.f / PER_BATCH_ELEMS) - mu * mu;
    float rs  = rsqrtf(var + GN_EPS);

    {   // load A tile (w_qkv rows o0..o0+64, all K), transposed into aT[k][o]
        int o  = threadIdx.x >> 2;
        int kb = (threadIdx.x & 3) * 32;
        const float4* src = (const float4*)(wqkv + (size_t)(o0 + o) * CIN + kb);
        #pragma unroll
        for (int j = 0; j < 8; j++) {
            float4 v = src[j];
            int k = kb + j * 4;
            aT[k][o] = v.x; aT[k + 1][o] = v.y; aT[k + 2][o] = v.z; aT[k + 3][o] = v.w;
        }
    }
    {   // load B tile: xn[k][n0..n0+64), groupnorm applied on the fly
        #pragma unroll
        for (int kk = 0; kk < 128; kk += 64) {
            int k  = kk + (threadIdx.x >> 2);
            int nb = (threadIdx.x & 3) * 16;
            const float4* src = (const float4*)(x + (size_t)b * PER_BATCH_ELEMS +
                                                (size_t)k * NTOK + n0 + nb);
            float g  = gw[k] * rs;
            float bb = gb[k] - mu * g;
            float4* dst = (float4*)&bT[k][nb];
            #pragma unroll
            for (int j = 0; j < 4; j++) {
                float4 v = src[j];
                float4 r = { v.x * g + bb, v.y * g + bb, v.z * g + bb, v.w * g + bb };
                dst[j] = r;
            }
        }
    }
    __syncthreads();

    int tn = threadIdx.x & 15, to = threadIdx.x >> 4;
    float acc[4][4] = {};
    for (int k = 0; k < 128; k++) {
        float4 va = *(const float4*)&aT[k][to * 4];
        float4 vb = *(const float4*)&bT[k][tn * 4];
        float a[4] = { va.x, va.y, va.z, va.w };
        float bv[4] = { vb.x, vb.y, vb.z, vb.w };
        #pragma unroll
        for (int i = 0; i < 4; i++)
            #pragma unroll
            for (int j = 0; j < 4; j++)
                acc[i][j] += a[i] * bv[j];
    }
    float* outp = qkv + (size_t)b * (QKV_ROWS * NTOK);
    #pragma unroll
    for (int i = 0; i < 4; i++) {
        float4 v = { acc[i][0], acc[i][1], acc[i][2], acc[i][3] };
        *(float4*)(outp + (size_t)(o0 + to * 4 + i) * NTOK + n0 + tn * 4) = v;
    }
}

// ---------------------------------------------------------------------------
// K3: q softmax over the 1024 spatial tokens, per (b, o<128) row. In place, *SCALE.
// grid (2048), block 256.
__global__ __launch_bounds__(256) void k_qsm(float* __restrict__ qkv) {
    __shared__ float red[8];
    int b = blockIdx.x >> 7, o = blockIdx.x & 127;
    float4* r4 = (float4*)(qkv + (size_t)b * (QKV_ROWS * NTOK) + (size_t)o * NTOK);
    float4 v = r4[threadIdx.x];
    float m = fmaxf(fmaxf(v.x, v.y), fmaxf(v.z, v.w));
    for (int off = 32; off; off >>= 1) m = fmaxf(m, __shfl_xor(m, off));
    int wid = threadIdx.x >> 6;
    if ((threadIdx.x & 63) == 0) red[wid] = m;
    __syncthreads();
    m = fmaxf(fmaxf(red[0], red[1]), fmaxf(red[2], red[3]));
    v.x = __expf(v.x - m); v.y = __expf(v.y - m);
    v.z = __expf(v.z - m); v.w = __expf(v.w - m);
    float s = v.x + v.y + v.z + v.w;
    for (int off = 32; off; off >>= 1) s += __shfl_xor(s, off);
    if ((threadIdx.x & 63) == 0) red[4 + wid] = s;
    __syncthreads();
    s = red[4] + red[5] + red[6] + red[7];
    float inv = SCALE_Q / s;
    v.x *= inv; v.y *= inv; v.z *= inv; v.w *= inv;
    r4[threadIdx.x] = v;
}

// ---------------------------------------------------------------------------
// K4: k softmax over 32 channels (per token) fused with M[c'][c] += k_sm*q_sm.
// grid (16, 4, 8) = (batch, head, n-chunk of 128). block 256. atomicAdd into M.
__global__ __launch_bounds__(256) void k_ksm_M(const float* __restrict__ qkv,
                                               float* __restrict__ M) {
    __shared__ float kl[128][33];
    __shared__ float ql[128][33];
    int b = blockIdx.x, h = blockIdx.y, n0 = blockIdx.z * 128;
    const float* base = qkv + (size_t)b * (QKV_ROWS * NTOK);
    {
        int cp = threadIdx.x >> 3;            // 0..31
        int nb = (threadIdx.x & 7) * 16;      // 0..112
        const float4* srck = (const float4*)(base + (size_t)(128 + h * 32 + cp) * NTOK + n0 + nb);
        const float4* srcq = (const float4*)(base + (size_t)(h * 32 + cp) * NTOK + n0 + nb);
        #pragma unroll
        for (int j = 0; j < 4; j++) {
            float4 kv = srck[j];
            float4 qv = srcq[j];
            int n = nb + j * 4;
            kl[n][cp] = kv.x; kl[n + 1][cp] = kv.y; kl[n + 2][cp] = kv.z; kl[n + 3][cp] = kv.w;
            ql[n][cp] = qv.x; ql[n + 1][cp] = qv.y; ql[n + 2][cp] = qv.z; ql[n + 3][cp] = qv.w;
        }
    }
    __syncthreads();
    if (threadIdx.x < 128) {   // softmax k over channels, per token
        int n = threadIdx.x;
        float m = -1e30f;
        #pragma unroll
        for (int c = 0; c < 32; c++) m = fmaxf(m, kl[n][c]);
        float s = 0.f;
        #pragma unroll
        for (int c = 0; c < 32; c++) { float e = __expf(kl[n][c] - m); kl[n][c] = e; s += e; }
        float inv = 1.f / s;
        #pragma unroll
        for (int c = 0; c < 32; c++) kl[n][c] *= inv;
    }
    __syncthreads();
    int c = threadIdx.x & 31, g = threadIdx.x >> 5;   // g in 0..7
    float a0 = 0, a1 = 0, a2 = 0, a3 = 0;
    for (int n = 0; n < 128; n++) {
        float qv = ql[n][c];
        a0 += kl[n][g] * qv;
        a1 += kl[n][g + 8] * qv;
        a2 += kl[n][g + 16] * qv;
        a3 += kl[n][g + 24] * qv;
    }
    float* Mp = M + ((size_t)b * 4 + h) * 1024;
    atomicAdd(&Mp[g * 32 + c], a0);
    atomicAdd(&Mp[(g + 8) * 32 + c], a1);
    atomicAdd(&Mp[(g + 16) * 32 + c], a2);
    atomicAdd(&Mp[(g + 24) * 32 + c], a3);
}

// ---------------------------------------------------------------------------
// K5: fold M into w_out:  W2[o][h*32+c'] = sum_c w_out[o][h*32+c] * M[h][c'][c]
// grid (16, 4) = (batch, o-tile of 32). block 256.
__global__ __launch_bounds__(256) void k_fold(const float* __restrict__ wout,
                                              const float* __restrict__ M,
                                              float* __restrict__ W2) {
    __shared__ float Ml[4][32][33];
    __shared__ __align__(16) float wl[32][132];
    int b = blockIdx.x, o0 = blockIdx.y * 32;
    {
        const float* Mb = M + (size_t)b * 4096;
        for (int i = threadIdx.x; i < 4096; i += 256) {
            int h = i >> 10, cp = (i >> 5) & 31, c = i & 31;
            Ml[h][cp][c] = Mb[i];
        }
        const float4* wsrc = (const float4*)(wout + (size_t)o0 * CIN);
        for (int i = threadIdx.x; i < 1024; i += 256) {
            int o = i >> 5, c4 = i & 31;
            ((float4*)&wl[o][0])[c4] = wsrc[i];
        }
    }
    __syncthreads();
    int ol = threadIdx.x >> 3;
    int j0 = (threadIdx.x & 7) * 16;
    int h = j0 >> 5;          // constant per thread (j0 is 16-aligned)
    int cp0 = j0 & 31;        // 0 or 16
    float s[16] = {};
    for (int c = 0; c < 32; c++) {
        float wv = wl[ol][h * 32 + c];
        #pragma unroll
        for (int jj = 0; jj < 16; jj++) s[jj] += wv * Ml[h][cp0 + jj][c];
    }
    float* out = W2 + (size_t)b * 16384 + (size_t)(o0 + ol) * CIN;
    #pragma unroll
    for (int jj = 0; jj < 16; jj++) out[j0 + jj] = s[jj];
}

// ---------------------------------------------------------------------------
// K6: y = W2 @ V + b_out.  per-batch 128x1024, K=128 (V = raw qkv rows 256..384).
// grid (2, 16, 16). block 256. Same structure as K2.
__global__ __launch_bounds__(256) void k_out(const float* __restrict__ qkv,
                                             const float* __restrict__ W2,
                                             const float* __restrict__ bout,
                                             float* __restrict__ y) {
    __shared__ __align__(16) float aT[128][64];
    __shared__ __align__(16) float bT[128][64];
    int b = blockIdx.z, o0 = blockIdx.x * 64, n0 = blockIdx.y * 64;
    {
        int o  = threadIdx.x >> 2;
        int kb = (threadIdx.x & 3) * 32;
        const float4* src = (const float4*)(W2 + (size_t)b * 16384 + (size_t)(o0 + o) * CIN + kb);
        #pragma unroll
        for (int j = 0; j < 8; j++) {
            float4 v = src[j];
            int k = kb + j * 4;
            aT[k][o] = v.x; aT[k + 1][o] = v.y; aT[k + 2][o] = v.z; aT[k + 3][o] = v.w;
        }
    }
    {
        #pragma unroll
        for (int kk = 0; kk < 128; kk += 64) {
            int k  = kk + (threadIdx.x >> 2);
            int nb = (threadIdx.x & 3) * 16;
            const float4* src = (const float4*)(qkv + (size_t)b * (QKV_ROWS * NTOK) +
                                                (size_t)(256 + k) * NTOK + n0 + nb);
            float4* dst = (float4*)&bT[k][nb];
            #pragma unroll
            for (int j = 0; j < 4; j++) dst[j] = src[j];
        }
    }
    __syncthreads();

    int tn = threadIdx.x & 15, to = threadIdx.x >> 4;
    float acc[4][4] = {};
    for (int k = 0; k < 128; k++) {
        float4 va = *(const float4*)&aT[k][to * 4];
        float4 vb = *(const float4*)&bT[k][tn * 4];
        float a[4] = { va.x, va.y, va.z, va.w };
        float bv[4] = { vb.x, vb.y, vb.z, vb.w };
        #pragma unroll
        for (int i = 0; i < 4; i++)
            #pragma unroll
            for (int j = 0; j < 4; j++)
                acc[i][j] += a[i] * bv[j];
    }
    #pragma unroll
    for (int i = 0; i < 4; i++) {
        int o = o0 + to * 4 + i;
        float bias = bout[o];
        float4 v = { acc[i][0] + bias, acc[i][1] + bias, acc[i][2] + bias, acc[i][3] + bias };
        *(float4*)(y + (size_t)b * PER_BATCH_ELEMS + (size_t)o * NTOK + n0 + tn * 4) = v;
    }
}

// ---------------------------------------------------------------------------
extern "C" void kernel_launch(void* const* d_in, const int* in_sizes, int n_in,
                              void* d_out, int out_size, void* d_ws, size_t ws_size,
                              hipStream_t stream) {
    const float* x    = (const float*)d_in[0];
    const float* gw   = (const float*)d_in[1];
    const float* gb   = (const float*)d_in[2];
    const float* wqkv = (const float*)d_in[3];
    const float* wout = (const float*)d_in[4];
    const float* bout = (const float*)d_in[5];
    float* y  = (float*)d_out;
    float* ws = (float*)d_ws;

    float* stats = ws + WS_STATS;
    float* M     = ws + WS_M;
    float* W2    = ws + WS_W2;
    float* qkv   = ws + WS_QKV;

    // zero the atomic accumulators (stats + M); ws is poisoned before each call
    hipMemsetAsync(stats, 0, (32 + 65536) * sizeof(float), stream);

    k_stats<<<dim3(16, 32), 256, 0, stream>>>(x, stats);
    k_qkv  <<<dim3(6, 16, 16), 256, 0, stream>>>(x, gw, gb, wqkv, stats, qkv);
    k_qsm  <<<dim3(2048), 256, 0, stream>>>(qkv);
    k_ksm_M<<<dim3(16, 4, 8), 256, 0, stream>>>(qkv, M);
    k_fold <<<dim3(16, 4), 256, 0, stream>>>(wout, M, W2);
    k_out  <<<dim3(2, 16, 16), 256, 0, stream>>>(qkv, W2, bout, y);
}

// Round 2
// 119.135 us; speedup vs baseline: 1.1731x; 1.1731x over previous
//
#include <hip/hip_runtime.h>
#include <math.h>

// B=16, C=128, H=W=32, N=1024, HEADS=4, DIM_HEAD=32, qkv rows=384.
#define NBATCH 16
#define CIN 128
#define NTOK 1024
#define SCALE_Q 0.17677669529663687f /* 32^-0.5 */
#define GN_EPS 1e-5f
#define PB (CIN * NTOK) /* 131072 */

// ---------------- workspace layout (float units) ----------------
// stats [16][2]            @0       (zeroed)
// qsum  [16][128]          @32      (zeroed)   sum_n exp(q[n][c])
// M     [16][4][32][32]    @2080    (zeroed)   fp32 atomically accumulated
// ksum  [16][4][1024]      @67616              sum_c exp(k[n][c]) per head
// W2b   [16][128][128]bf16 @133152 (131072 fl)
// wqkvb [384][128] bf16    @264224 (24576 fl)
// xT    [16][1024][128]bf16@288800 (1048576 fl)
// qkvT  [16][1024][384]f32 @1337376 (6291456 fl)
#define WS_STATS 0
#define WS_QSUM 32
#define WS_M 2080
#define WS_KSUM 67616
#define WS_W2 133152
#define WS_WQKVB 264224
#define WS_XT 288800
#define WS_QKVT 1337376

typedef __bf16 bf16x8 __attribute__((ext_vector_type(8)));
typedef float f32x4 __attribute__((ext_vector_type(4)));

__device__ __forceinline__ unsigned short f2bf(float f) {
    union { float f; unsigned u; } v; v.f = f;
    unsigned r = v.u + 0x7fffu + ((v.u >> 16) & 1u);
    return (unsigned short)(r >> 16);
}
__device__ __forceinline__ unsigned pack2(float a, float b) {
    return (unsigned)f2bf(a) | ((unsigned)f2bf(b) << 16);
}

// ---------------------------------------------------------------------------
// K1: per-batch sum/sumsq (grid y<32) + wqkv->bf16 convert (grid y==32).
__global__ __launch_bounds__(256) void k_stats(const float* __restrict__ x,
                                               const float* __restrict__ wqkv,
                                               float* __restrict__ stats,
                                               unsigned short* __restrict__ wqkvb) {
    if (blockIdx.y == 32) {
        int base = blockIdx.x * 3072;  // 16 blocks x 3072 = 49152
        const float4* src = (const float4*)(wqkv + base);
        for (int i = threadIdx.x; i < 768; i += 256) {
            float4 v = src[i];
            uint2 p; p.x = pack2(v.x, v.y); p.y = pack2(v.z, v.w);
            *(uint2*)(wqkvb + base + i * 4) = p;
        }
        return;
    }
    int b = blockIdx.x, chunk = blockIdx.y;
    const float4* p = (const float4*)(x + (size_t)b * PB + chunk * 4096);
    float s = 0.f, s2 = 0.f;
    for (int i = threadIdx.x; i < 1024; i += 256) {
        float4 v = p[i];
        s += v.x + v.y + v.z + v.w;
        s2 += v.x * v.x + v.y * v.y + v.z * v.z + v.w * v.w;
    }
    for (int off = 32; off; off >>= 1) {
        s += __shfl_down(s, off);
        s2 += __shfl_down(s2, off);
    }
    __shared__ float ls[4], ls2[4];
    int wid = threadIdx.x >> 6, lane = threadIdx.x & 63;
    if (lane == 0) { ls[wid] = s; ls2[wid] = s2; }
    __syncthreads();
    if (threadIdx.x == 0) {
        float t = 0, t2 = 0;
        for (int w = 0; w < 4; w++) { t += ls[w]; t2 += ls2[w]; }
        atomicAdd(&stats[b * 2], t);
        atomicAdd(&stats[b * 2 + 1], t2);
    }
}

// ---------------------------------------------------------------------------
// K2: xT[b][n][c] = bf16(groupnorm(x)[c][n]).  grid (16 ntile, 16 b), 256 thr.
__global__ __launch_bounds__(256) void k_normT(const float* __restrict__ x,
                                               const float* __restrict__ gw,
                                               const float* __restrict__ gb,
                                               const float* __restrict__ stats,
                                               unsigned short* __restrict__ xT) {
    __shared__ float Xl[128][68];
    int b = blockIdx.y, n0 = blockIdx.x * 64;
    float mu = stats[b * 2] * (1.f / PB);
    float var = stats[b * 2 + 1] * (1.f / PB) - mu * mu;
    float rs = rsqrtf(var + GN_EPS);
    int k = threadIdx.x >> 1, hf = threadIdx.x & 1;
    float g = gw[k] * rs, bb = gb[k] - mu * g;
    const float4* src = (const float4*)(x + ((size_t)b * CIN + k) * NTOK + n0 + hf * 32);
    #pragma unroll
    for (int i = 0; i < 8; i++) {
        float4 v = src[i];
        float4 r = { v.x * g + bb, v.y * g + bb, v.z * g + bb, v.w * g + bb };
        *(float4*)&Xl[k][hf * 32 + i * 4] = r;
    }
    __syncthreads();
    int n = threadIdx.x & 63, kq = (threadIdx.x >> 6) * 32;
    unsigned pk[16];
    #pragma unroll
    for (int j = 0; j < 16; j++)
        pk[j] = pack2(Xl[kq + 2 * j][n], Xl[kq + 2 * j + 1][n]);
    unsigned short* dst = xT + ((size_t)b * NTOK + n0 + n) * CIN + kq;
    #pragma unroll
    for (int j = 0; j < 4; j++)
        *(uint4*)(dst + j * 8) = *(uint4*)(pk + j * 4);
}

// ---------------------------------------------------------------------------
// K3: qkvT[b][n][o] = sum_k xT[n][k]*wqkv[o][k]  (MFMA bf16, fp32 out).
// Fuses qsum (o-tile 0, atomic) and ksum (o-tile 1, direct) epilogues.
// grid (16 ntile64, 3 otile128, 16 b), 256 thr = 4 waves (wave: n32 x o64).
__global__ __launch_bounds__(256) void k_gemm1(const unsigned short* __restrict__ xT,
                                               const unsigned short* __restrict__ wqkvb,
                                               float* __restrict__ qkvT,
                                               float* __restrict__ qsum,
                                               float* __restrict__ ksum) {
    __shared__ unsigned short Al[64][136];
    __shared__ unsigned short Bl[128][136];
    int b = blockIdx.z, o0 = blockIdx.y * 128, n0 = blockIdx.x * 64;
    int t = threadIdx.x;
    {   // stage A: xT rows n0..n0+63 (128 bf16 each)
        int row = t >> 2, q = t & 3;
        const uint4* src = (const uint4*)(xT + ((size_t)b * NTOK + n0 + row) * CIN + q * 32);
        uint4* dst = (uint4*)&Al[row][q * 32];
        #pragma unroll
        for (int j = 0; j < 4; j++) dst[j] = src[j];
    }
    {   // stage B: wqkvb rows o0..o0+127
        int row = t >> 1, hf = t & 1;
        const uint4* src = (const uint4*)(wqkvb + (size_t)(o0 + row) * CIN + hf * 64);
        uint4* dst = (uint4*)&Bl[row][hf * 64];
        #pragma unroll
        for (int j = 0; j < 8; j++) dst[j] = src[j];
    }
    __syncthreads();
    int lane = t & 63, wave = t >> 6;
    int wn0 = (wave & 1) * 32, wo0 = (wave >> 1) * 64;
    int l15 = lane & 15, lk = (lane >> 4) * 8;
    f32x4 acc[2][4] = {};
    #pragma unroll
    for (int ks = 0; ks < 4; ks++) {
        bf16x8 av[2], bv[4];
        #pragma unroll
        for (int i = 0; i < 2; i++) av[i] = *(const bf16x8*)&Al[wn0 + i * 16 + l15][ks * 32 + lk];
        #pragma unroll
        for (int j = 0; j < 4; j++) bv[j] = *(const bf16x8*)&Bl[wo0 + j * 16 + l15][ks * 32 + lk];
        #pragma unroll
        for (int i = 0; i < 2; i++)
            #pragma unroll
            for (int j = 0; j < 4; j++)
                acc[i][j] = __builtin_amdgcn_mfma_f32_16x16x32_bf16(av[i], bv[j], acc[i][j], 0, 0, 0);
    }
    // store qkvT (fp32)
    #pragma unroll
    for (int i = 0; i < 2; i++)
        #pragma unroll
        for (int r = 0; r < 4; r++) {
            int nrow = n0 + wn0 + i * 16 + (lane >> 4) * 4 + r;
            float* rp = qkvT + ((size_t)b * NTOK + nrow) * 384 + o0 + wo0;
            #pragma unroll
            for (int j = 0; j < 4; j++) rp[j * 16 + l15] = acc[i][j][r];
        }
    if (blockIdx.y == 0) {  // q: column sums of exp over this block's 64 n-rows
        #pragma unroll
        for (int j = 0; j < 4; j++) {
            float s = 0.f;
            #pragma unroll
            for (int i = 0; i < 2; i++)
                #pragma unroll
                for (int r = 0; r < 4; r++) s += __expf(acc[i][j][r]);
            s += __shfl_xor(s, 16);
            s += __shfl_xor(s, 32);
            if ((lane >> 4) == 0)
                atomicAdd(&qsum[b * 128 + wo0 + j * 16 + l15], s);
        }
    } else if (blockIdx.y == 1) {  // k: per-(n,head) sums of exp over 32 channels
        #pragma unroll
        for (int i = 0; i < 2; i++)
            #pragma unroll
            for (int r = 0; r < 4; r++) {
                float e01 = __expf(acc[i][0][r]) + __expf(acc[i][1][r]);
                float e23 = __expf(acc[i][2][r]) + __expf(acc[i][3][r]);
                #pragma unroll
                for (int m = 1; m < 16; m <<= 1) {
                    e01 += __shfl_xor(e01, m);
                    e23 += __shfl_xor(e23, m);
                }
                if (l15 == 0) {
                    int nrow = n0 + wn0 + i * 16 + (lane >> 4) * 4 + r;
                    int h0 = (wave >> 1) * 2;
                    ksum[((size_t)b * 4 + h0) * NTOK + nrow] = e01;
                    ksum[((size_t)b * 4 + h0 + 1) * NTOK + nrow] = e23;
                }
            }
    }
}

// ---------------------------------------------------------------------------
// K4: M[b][h][c'][c] += sum_n k_sm[n][c'] * q_sm[n][c]   (fp32 atomics)
// grid (8 nchunk128, 4 h, 16 b), 256 thr.
__global__ __launch_bounds__(256) void k_M(const float* __restrict__ qkvT,
                                           const float* __restrict__ qsum,
                                           const float* __restrict__ ksum,
                                           float* __restrict__ Mg) {
    __shared__ float ql[128][36];
    __shared__ float kl[128][36];
    __shared__ float kinv[128];
    __shared__ float qsc[32];
    int n0 = blockIdx.x * 128, h = blockIdx.y, b = blockIdx.z;
    int t = threadIdx.x;
    const float* base = qkvT + ((size_t)b * NTOK + n0) * 384;
    int row = t >> 1, hf = t & 1;
    const float4* qs = (const float4*)(base + (size_t)row * 384 + h * 32 + hf * 16);
    const float4* ks2 = (const float4*)(base + (size_t)row * 384 + 128 + h * 32 + hf * 16);
    #pragma unroll
    for (int j = 0; j < 4; j++) {
        *(float4*)&ql[row][hf * 16 + j * 4] = qs[j];
        *(float4*)&kl[row][hf * 16 + j * 4] = ks2[j];
    }
    if (t < 128) kinv[t] = 1.0f / ksum[((size_t)b * 4 + h) * NTOK + n0 + t];
    else if (t < 160) qsc[t - 128] = SCALE_Q / qsum[b * 128 + h * 32 + (t - 128)];
    __syncthreads();
    #pragma unroll
    for (int i = 0; i < 16; i++) {
        int idx = t * 16 + i;
        int r = idx >> 5, c = idx & 31;
        kl[r][c] = __expf(kl[r][c]) * kinv[r];
        ql[r][c] = __expf(ql[r][c]) * qsc[c];
    }
    __syncthreads();
    int c = t & 31, cp = (t >> 5) * 4;
    float a0 = 0, a1 = 0, a2 = 0, a3 = 0;
    for (int n = 0; n < 128; n++) {
        float qv = ql[n][c];
        a0 += kl[n][cp + 0] * qv;
        a1 += kl[n][cp + 1] * qv;
        a2 += kl[n][cp + 2] * qv;
        a3 += kl[n][cp + 3] * qv;
    }
    float* Mp = Mg + ((size_t)b * 4 + h) * 1024;
    atomicAdd(&Mp[(cp + 0) * 32 + c], a0);
    atomicAdd(&Mp[(cp + 1) * 32 + c], a1);
    atomicAdd(&Mp[(cp + 2) * 32 + c], a2);
    atomicAdd(&Mp[(cp + 3) * 32 + c], a3);
}

// ---------------------------------------------------------------------------
// K5: W2[o][h*32+c'] = sum_c wout[o][h*32+c] * M[h][c'][c]  -> bf16
// grid (16 b, 8 osplit16), 256 thr, register-only (M is L1-resident).
__global__ __launch_bounds__(256) void k_fold(const float* __restrict__ wout,
                                              const float* __restrict__ Mg,
                                              unsigned short* __restrict__ W2b) {
    int b = blockIdx.x, o0 = blockIdx.y * 16;
    int t = threadIdx.x;
    int cg = t & 127;   // output channel c'(global across heads)
    int og = t >> 7;    // 0..1
    int hh = cg >> 5, cl = cg & 31;
    const float4* m4 = (const float4*)(Mg + ((size_t)b * 4 + hh) * 1024 + cl * 32);
    float4 m[8];
    #pragma unroll
    for (int i = 0; i < 8; i++) m[i] = m4[i];
    #pragma unroll
    for (int oi = 0; oi < 8; oi++) {
        int o = o0 + og * 8 + oi;
        const float4* w4 = (const float4*)(wout + o * 128 + hh * 32);
        float acc = 0.f;
        #pragma unroll
        for (int i = 0; i < 8; i++) {
            float4 w = w4[i];
            acc += w.x * m[i].x + w.y * m[i].y + w.z * m[i].z + w.w * m[i].w;
        }
        W2b[((size_t)b * 128 + o) * 128 + cg] = f2bf(acc);
    }
}

// ---------------------------------------------------------------------------
// K6: y[b][o][n] = sum_c' W2[o][c'] * v[n][c'] + bout[o]   (MFMA bf16)
// v[n][c'] = qkvT[b][n][256+c'].  grid (16 ntile64, 16 b), 256 thr.
__global__ __launch_bounds__(256) void k_gemm2(const float* __restrict__ qkvT,
                                               const unsigned short* __restrict__ W2b,
                                               const float* __restrict__ bout,
                                               float* __restrict__ y) {
    __shared__ unsigned short Wl[128][136];
    __shared__ unsigned short Vl[64][136];
    int n0 = blockIdx.x * 64, b = blockIdx.y;
    int t = threadIdx.x;
    {   int row = t >> 1, hf = t & 1;
        const uint4* src = (const uint4*)(W2b + ((size_t)b * 128 + row) * 128 + hf * 64);
        uint4* dst = (uint4*)&Wl[row][hf * 64];
        #pragma unroll
        for (int j = 0; j < 8; j++) dst[j] = src[j];
    }
    {   int n = t >> 2, q = t & 3;
        const float4* src = (const float4*)(qkvT + ((size_t)b * NTOK + n0 + n) * 384 + 256 + q * 32);
        #pragma unroll
        for (int j = 0; j < 4; j++) {
            float4 a = src[2 * j];
            float4 c = src[2 * j + 1];
            uint4 pv;
            pv.x = pack2(a.x, a.y); pv.y = pack2(a.z, a.w);
            pv.z = pack2(c.x, c.y); pv.w = pack2(c.z, c.w);
            *(uint4*)&Vl[n][q * 32 + j * 8] = pv;
        }
    }
    __syncthreads();
    int lane = t & 63, wave = t >> 6;
    int wo0 = (wave >> 1) * 64, wn0 = (wave & 1) * 32;
    int l15 = lane & 15, lk = (lane >> 4) * 8;
    f32x4 acc[4][2] = {};
    #pragma unroll
    for (int ks = 0; ks < 4; ks++) {
        bf16x8 av[4], bv[2];
        #pragma unroll
        for (int i = 0; i < 4; i++) av[i] = *(const bf16x8*)&Wl[wo0 + i * 16 + l15][ks * 32 + lk];
        #pragma unroll
        for (int j = 0; j < 2; j++) bv[j] = *(const bf16x8*)&Vl[wn0 + j * 16 + l15][ks * 32 + lk];
        #pragma unroll
        for (int i = 0; i < 4; i++)
            #pragma unroll
            for (int j = 0; j < 2; j++)
                acc[i][j] = __builtin_amdgcn_mfma_f32_16x16x32_bf16(av[i], bv[j], acc[i][j], 0, 0, 0);
    }
    #pragma unroll
    for (int i = 0; i < 4; i++)
        #pragma unroll
        for (int r = 0; r < 4; r++) {
            int o = wo0 + i * 16 + (lane >> 4) * 4 + r;
            float bias = bout[o];
            float* rp = y + ((size_t)b * CIN + o) * NTOK + n0 + wn0;
            #pragma unroll
            for (int j = 0; j < 2; j++) rp[j * 16 + l15] = acc[i][j][r] + bias;
        }
}

// ---------------------------------------------------------------------------
extern "C" void kernel_launch(void* const* d_in, const int* in_sizes, int n_in,
                              void* d_out, int out_size, void* d_ws, size_t ws_size,
                              hipStream_t stream) {
    const float* x = (const float*)d_in[0];
    const float* gw = (const float*)d_in[1];
    const float* gb = (const float*)d_in[2];
    const float* wqkv = (const float*)d_in[3];
    const float* wout = (const float*)d_in[4];
    const float* bout = (const float*)d_in[5];
    float* y = (float*)d_out;
    float* ws = (float*)d_ws;

    float* stats = ws + WS_STATS;
    float* qsum = ws + WS_QSUM;
    float* Mg = ws + WS_M;
    float* ksum = ws + WS_KSUM;
    unsigned short* W2b = (unsigned short*)(ws + WS_W2);
    unsigned short* wqkvb = (unsigned short*)(ws + WS_WQKVB);
    unsigned short* xT = (unsigned short*)(ws + WS_XT);
    float* qkvT = ws + WS_QKVT;

    // zero stats + qsum + M (atomic accumulators)
    hipMemsetAsync(stats, 0, (size_t)67616 * sizeof(float), stream);

    k_stats<<<dim3(16, 33), 256, 0, stream>>>(x, wqkv, stats, wqkvb);
    k_normT<<<dim3(16, 16), 256, 0, stream>>>(x, gw, gb, stats, xT);
    k_gemm1<<<dim3(16, 3, 16), 256, 0, stream>>>(xT, wqkvb, qkvT, qsum, ksum);
    k_M<<<dim3(8, 4, 16), 256, 0, stream>>>(qkvT, qsum, ksum, Mg);
    k_fold<<<dim3(16, 8), 256, 0, stream>>>(wout, Mg, W2b);
    k_gemm2<<<dim3(16, 16), 256, 0, stream>>>(qkvT, W2b, bout, y);
}